// Round 1
// baseline (716.666 us; speedup 1.0000x reference)
//
#include <hip/hip_runtime.h>
#include <math.h>

#define N_NODES 50000
#define N_EDGES 800000
#define N_GRAPHS 64
#define NREP 32
#define LN_EPS 1e-5f

// ---------------- cross-lane reductions ----------------
__device__ __forceinline__ float red16(float p) {
  p += __shfl_xor(p, 1); p += __shfl_xor(p, 2);
  p += __shfl_xor(p, 4); p += __shfl_xor(p, 8);
  return p;
}
__device__ __forceinline__ float red64(float p) {
  p += __shfl_xor(p, 1);  p += __shfl_xor(p, 2);  p += __shfl_xor(p, 4);
  p += __shfl_xor(p, 8);  p += __shfl_xor(p, 16); p += __shfl_xor(p, 32);
  return p;
}

// ---------------- K1: per-dst degree + edge_attr sum ----------------
__global__ void k_hist(const int* __restrict__ dst, const float* __restrict__ ea,
                       int* __restrict__ deg, float* __restrict__ easum) {
  int e = blockIdx.x * 256 + threadIdx.x;
  if (e >= N_EDGES) return;
  int d = dst[e];
  atomicAdd(&deg[d], 1);
  atomicAdd(&easum[d], ea[e]);
}

// ---------------- K2: exclusive scan of deg -> offsets (1 block) ----------------
__global__ void k_scan(const int* __restrict__ deg, int* __restrict__ offsets) {
  __shared__ int part[1024];
  int t = threadIdx.x;
  const int CH = (N_NODES + 1023) / 1024;  // 49
  int lo = t * CH, hi = min(lo + CH, N_NODES);
  int s = 0;
  for (int i = lo; i < hi; ++i) s += deg[i];
  part[t] = s;
  __syncthreads();
  for (int off = 1; off < 1024; off <<= 1) {
    int v = (t >= off) ? part[t - off] : 0;
    __syncthreads();
    part[t] += v;
    __syncthreads();
  }
  int run = (t == 0) ? 0 : part[t - 1];
  for (int i = lo; i < hi; ++i) { offsets[i] = run; run += deg[i]; }
  if (t == 0) offsets[N_NODES] = N_EDGES;
}

// ---------------- K3: counting-sort scatter (edges grouped by dst) ----------------
__global__ void k_scatter(const int* __restrict__ src, const int* __restrict__ dst,
                          const float* __restrict__ ea, const int* __restrict__ offsets,
                          int* __restrict__ cursor, int* __restrict__ ssrc,
                          float* __restrict__ sea) {
  int e = blockIdx.x * 256 + threadIdx.x;
  if (e >= N_EDGES) return;
  int d = dst[e];
  int pos = offsets[d] + atomicAdd(&cursor[d], 1);
  ssrc[pos] = src[e];
  sea[pos]  = ea[e];
}

// ---------------- K4: fused GATv2 layer 1 + bias + LN + ELU ----------------
// one wave per node; lane owns 4 channels (c0=lane*4), head = lane/16.
__global__ __launch_bounds__(256) void k_gat1(
    const float* __restrict__ x,
    const float* __restrict__ Wl, const float* __restrict__ Wr,
    const float* __restrict__ We, const float* __restrict__ att,
    const float* __restrict__ b1, const float* __restrict__ g1, const float* __restrict__ be1,
    const int* __restrict__ offsets, const int* __restrict__ ssrc,
    const float* __restrict__ sea,
    const int* __restrict__ deg, const float* __restrict__ easum,
    float* __restrict__ h1) {
  int lane = threadIdx.x & 63;
  int n = blockIdx.x * 4 + (threadIdx.x >> 6);   // grid is exact: 12500*4 = 50000
  int c0 = lane * 4;

  float4 wev = *(const float4*)(We + c0);   // We1 column coeffs (edge_dim=1)
  float4 atv = *(const float4*)(att + c0);  // att1 flat layout == channel layout

  float xn[8];
  {
    float4 a = *(const float4*)(x + n * 8);
    float4 b = *(const float4*)(x + n * 8 + 4);
    xn[0]=a.x; xn[1]=a.y; xn[2]=a.z; xn[3]=a.w;
    xn[4]=b.x; xn[5]=b.y; xn[6]=b.z; xn[7]=b.w;
  }
  // xr = x[n] @ Wr  (target transform, loop-invariant for this node)
  float xr0=0.f, xr1=0.f, xr2=0.f, xr3=0.f;
#pragma unroll
  for (int k = 0; k < 8; ++k) {
    float4 w = *(const float4*)(Wr + k * 256 + c0);
    xr0 += xn[k]*w.x; xr1 += xn[k]*w.y; xr2 += xn[k]*w.z; xr3 += xn[k]*w.w;
  }
  // Wl columns held in registers: per-edge xl[src] recomputed from 32B of x
  float wl[8][4];
#pragma unroll
  for (int k = 0; k < 8; ++k) {
    float4 w = *(const float4*)(Wl + k * 256 + c0);
    wl[k][0]=w.x; wl[k][1]=w.y; wl[k][2]=w.z; wl[k][3]=w.w;
  }

  float mmax = -INFINITY, den = 0.f;
  float ac0=0.f, ac1=0.f, ac2=0.f, ac3=0.f;

  auto process = [&](float v0, float v1, float v2, float v3, float eav) {
    float m0 = v0 + xr0 + eav * wev.x; m0 = m0 > 0.f ? m0 : 0.2f * m0;
    float m1 = v1 + xr1 + eav * wev.y; m1 = m1 > 0.f ? m1 : 0.2f * m1;
    float m2 = v2 + xr2 + eav * wev.z; m2 = m2 > 0.f ? m2 : 0.2f * m2;
    float m3 = v3 + xr3 + eav * wev.w; m3 = m3 > 0.f ? m3 : 0.2f * m3;
    float p = m0*atv.x + m1*atv.y + m2*atv.z + m3*atv.w;
    p = red16(p);                       // head-group (16 lanes) dot reduce
    if (p > mmax) {                     // online softmax rescale
      float sc = __expf(mmax - p);
      den *= sc; ac0 *= sc; ac1 *= sc; ac2 *= sc; ac3 *= sc;
      mmax = p;
    }
    float w = __expf(p - mmax);
    den += w;
    ac0 += w * v0; ac1 += w * v1; ac2 += w * v2; ac3 += w * v3;
  };

  // self loop (fill_value='mean' edge attr)
  {
    float lea = easum[n] / fmaxf((float)deg[n], 1.0f);
    float v0=0.f,v1=0.f,v2=0.f,v3=0.f;
#pragma unroll
    for (int k = 0; k < 8; ++k) {
      v0 += xn[k]*wl[k][0]; v1 += xn[k]*wl[k][1];
      v2 += xn[k]*wl[k][2]; v3 += xn[k]*wl[k][3];
    }
    process(v0, v1, v2, v3, lea);
  }

  int beg = offsets[n], end = offsets[n + 1];
  if (beg < end) {
    int sCur = ssrc[beg];
    float eCur = sea[beg];
    float4 xaC = *(const float4*)(x + sCur * 8);
    float4 xbC = *(const float4*)(x + sCur * 8 + 4);
    for (int i = beg; i < end; ++i) {
      float4 xa = xaC, xb = xbC;
      float eav = eCur;
      if (i + 1 < end) {                 // prefetch next edge (hides x-gather latency)
        sCur = ssrc[i + 1]; eCur = sea[i + 1];
        xaC = *(const float4*)(x + sCur * 8);
        xbC = *(const float4*)(x + sCur * 8 + 4);
      }
      float xs[8] = {xa.x,xa.y,xa.z,xa.w,xb.x,xb.y,xb.z,xb.w};
      float v0=0.f,v1=0.f,v2=0.f,v3=0.f;
#pragma unroll
      for (int k = 0; k < 8; ++k) {
        v0 += xs[k]*wl[k][0]; v1 += xs[k]*wl[k][1];
        v2 += xs[k]*wl[k][2]; v3 += xs[k]*wl[k][3];
      }
      process(v0, v1, v2, v3, eav);
    }
  }

  float inv = 1.0f / (den + 1e-16f);
  float4 bv = *(const float4*)(b1 + c0);
  float o0 = ac0*inv + bv.x, o1 = ac1*inv + bv.y;
  float o2 = ac2*inv + bv.z, o3 = ac3*inv + bv.w;
  // LayerNorm over 256 (full-wave reduce)
  float mu = red64(o0 + o1 + o2 + o3) * (1.0f / 256.0f);
  float d0 = o0-mu, d1 = o1-mu, d2 = o2-mu, d3 = o3-mu;
  float rstd = rsqrtf(red64(d0*d0 + d1*d1 + d2*d2 + d3*d3) * (1.0f/256.0f) + LN_EPS);
  float4 gv  = *(const float4*)(g1 + c0);
  float4 bev = *(const float4*)(be1 + c0);
  float y0 = d0*rstd*gv.x + bev.x; y0 = y0 > 0.f ? y0 : __expf(y0) - 1.0f;
  float y1 = d1*rstd*gv.y + bev.y; y1 = y1 > 0.f ? y1 : __expf(y1) - 1.0f;
  float y2 = d2*rstd*gv.z + bev.z; y2 = y2 > 0.f ? y2 : __expf(y2) - 1.0f;
  float y3 = d3*rstd*gv.w + bev.w; y3 = y3 > 0.f ? y3 : __expf(y3) - 1.0f;
  float4 o; o.x=y0; o.y=y1; o.z=y2; o.w=y3;
  *(float4*)(h1 + (size_t)n * 256 + c0) = o;
}

// ---------------- K5: xl2 = h1@Wl2, xr2 = h1@Wr2 (tiled f32 GEMM) ----------------
// BM=64 nodes, BN=128 cols, BK=32; blockIdx.y selects {Wl2->xl2, Wr2->xr2}
__global__ __launch_bounds__(256) void k_gemm2(
    const float* __restrict__ h1, const float* __restrict__ Wl2,
    const float* __restrict__ Wr2, float* __restrict__ xl2, float* __restrict__ xr2) {
  __shared__ float As[32][64];    // [k][m]  (transposed for b128 fragment reads)
  __shared__ float Bs[32][128];   // [k][n]
  const float* B = blockIdx.y ? Wr2 : Wl2;
  float* C = blockIdx.y ? xr2 : xl2;
  int t = threadIdx.x;
  int bm0 = blockIdx.x * 64;
  int cg = t & 15, ng = t >> 4;
  int cc0 = cg * 8, m0 = ng * 4;
  float acc[4][8];
#pragma unroll
  for (int i = 0; i < 4; ++i)
#pragma unroll
    for (int j = 0; j < 8; ++j) acc[i][j] = 0.f;

  int lm = t & 63;           // A-load node
  int ks = (t >> 6) * 8;     // A-load k slice
  int brow = t >> 3;         // B-load k row
  int bcol = (t & 7) * 16;   // B-load col base

  for (int kc = 0; kc < 256; kc += 32) {
    int gm = bm0 + lm;
    float4 va, vb;
    if (gm < N_NODES) {
      va = *(const float4*)(h1 + (size_t)gm * 256 + kc + ks);
      vb = *(const float4*)(h1 + (size_t)gm * 256 + kc + ks + 4);
    } else { va = make_float4(0,0,0,0); vb = make_float4(0,0,0,0); }
    As[ks+0][lm]=va.x; As[ks+1][lm]=va.y; As[ks+2][lm]=va.z; As[ks+3][lm]=va.w;
    As[ks+4][lm]=vb.x; As[ks+5][lm]=vb.y; As[ks+6][lm]=vb.z; As[ks+7][lm]=vb.w;
#pragma unroll
    for (int j = 0; j < 4; ++j)
      *(float4*)(&Bs[brow][bcol + j*4]) =
        *(const float4*)(B + (size_t)(kc + brow) * 128 + bcol + j*4);
    __syncthreads();
#pragma unroll
    for (int k = 0; k < 32; ++k) {
      float4 a = *(const float4*)(&As[k][m0]);
      float4 p = *(const float4*)(&Bs[k][cc0]);
      float4 q = *(const float4*)(&Bs[k][cc0 + 4]);
      float av[4] = {a.x, a.y, a.z, a.w};
      float bv[8] = {p.x, p.y, p.z, p.w, q.x, q.y, q.z, q.w};
#pragma unroll
      for (int i = 0; i < 4; ++i)
#pragma unroll
        for (int j = 0; j < 8; ++j) acc[i][j] += av[i] * bv[j];
    }
    __syncthreads();
  }
#pragma unroll
  for (int i = 0; i < 4; ++i) {
    int gm = bm0 + m0 + i;
    if (gm < N_NODES) {
      float4 o0 = make_float4(acc[i][0], acc[i][1], acc[i][2], acc[i][3]);
      float4 o1 = make_float4(acc[i][4], acc[i][5], acc[i][6], acc[i][7]);
      *(float4*)(C + (size_t)gm * 128 + cc0)     = o0;
      *(float4*)(C + (size_t)gm * 128 + cc0 + 4) = o1;
    }
  }
}

// ---------------- K6: fused GATv2 layer 2 + bias + LN + ELU + pooled atomics --------
// one wave per node; lane owns 2 channels (c0=lane*2), single head.
__global__ __launch_bounds__(256) void k_gat2(
    const float* __restrict__ xl2, const float* __restrict__ xr2,
    const float* __restrict__ We, const float* __restrict__ att,
    const float* __restrict__ b2, const float* __restrict__ g2, const float* __restrict__ be2,
    const int* __restrict__ offsets, const int* __restrict__ ssrc,
    const float* __restrict__ sea,
    const int* __restrict__ deg, const float* __restrict__ easum,
    const int* __restrict__ batch,
    float* __restrict__ pool, float* __restrict__ cnt) {
  int lane = threadIdx.x & 63;
  int n = blockIdx.x * 4 + (threadIdx.x >> 6);
  int c0 = lane * 2;

  float2 wev = *(const float2*)(We + c0);
  float2 atv = *(const float2*)(att + c0);
  float2 xrv = *(const float2*)(xr2 + (size_t)n * 128 + c0);

  float mmax = -INFINITY, den = 0.f, a0 = 0.f, a1 = 0.f;
  auto process = [&](float v0, float v1, float eav) {
    float q0 = v0 + xrv.x + eav * wev.x; q0 = q0 > 0.f ? q0 : 0.2f * q0;
    float q1 = v1 + xrv.y + eav * wev.y; q1 = q1 > 0.f ? q1 : 0.2f * q1;
    float p = red64(q0 * atv.x + q1 * atv.y);
    if (p > mmax) { float sc = __expf(mmax - p); den *= sc; a0 *= sc; a1 *= sc; mmax = p; }
    float w = __expf(p - mmax);
    den += w; a0 += w * v0; a1 += w * v1;
  };

  {
    float lea = easum[n] / fmaxf((float)deg[n], 1.0f);
    float2 xv = *(const float2*)(xl2 + (size_t)n * 128 + c0);
    process(xv.x, xv.y, lea);
  }
  int beg = offsets[n], end = offsets[n + 1];
  if (beg < end) {
    int sCur = ssrc[beg];
    float eCur = sea[beg];
    float2 xc = *(const float2*)(xl2 + (size_t)sCur * 128 + c0);
    for (int i = beg; i < end; ++i) {
      float2 xv = xc; float eav = eCur;
      if (i + 1 < end) {
        sCur = ssrc[i + 1]; eCur = sea[i + 1];
        xc = *(const float2*)(xl2 + (size_t)sCur * 128 + c0);
      }
      process(xv.x, xv.y, eav);
    }
  }

  float inv = 1.0f / (den + 1e-16f);
  float2 bv = *(const float2*)(b2 + c0);
  float o0 = a0 * inv + bv.x, o1 = a1 * inv + bv.y;
  float mu = red64(o0 + o1) * (1.0f / 128.0f);
  float d0 = o0 - mu, d1 = o1 - mu;
  float rstd = rsqrtf(red64(d0*d0 + d1*d1) * (1.0f / 128.0f) + LN_EPS);
  float2 gv  = *(const float2*)(g2 + c0);
  float2 bev = *(const float2*)(be2 + c0);
  float y0 = d0*rstd*gv.x + bev.x; y0 = y0 > 0.f ? y0 : __expf(y0) - 1.0f;
  float y1 = d1*rstd*gv.y + bev.y; y1 = y1 > 0.f ? y1 : __expf(y1) - 1.0f;

  int g = batch[n];
  int r = blockIdx.x & (NREP - 1);            // replica slice -> low atomic contention
  float* pp = pool + ((size_t)(r * N_GRAPHS + g)) * 128 + c0;
  atomicAdd(pp, y0);
  atomicAdd(pp + 1, y1);
  if (lane == 0) atomicAdd(&cnt[r * N_GRAPHS + g], 1.0f);
}

// ---------------- K7: reduce replicas, divide by count ----------------
__global__ void k_final(const float* __restrict__ pool, const float* __restrict__ cnt,
                        float* __restrict__ out) {
  int idx = blockIdx.x * 256 + threadIdx.x;
  if (idx >= N_GRAPHS * 128) return;
  int g = idx >> 7, c = idx & 127;
  float s = 0.f, nn = 0.f;
#pragma unroll
  for (int r = 0; r < NREP; ++r) {
    s  += pool[((size_t)(r * N_GRAPHS + g)) * 128 + c];
    nn += cnt[r * N_GRAPHS + g];
  }
  out[idx] = s / fmaxf(nn, 1.0f);
}

// ---------------- launch ----------------
extern "C" void kernel_launch(void* const* d_in, const int* in_sizes, int n_in,
                              void* d_out, int out_size, void* d_ws, size_t ws_size,
                              hipStream_t stream) {
  const float* x    = (const float*)d_in[0];
  const int*   ei   = (const int*)  d_in[1];
  const float* ea   = (const float*)d_in[2];
  const int*   batch= (const int*)  d_in[3];
  const float* Wl1  = (const float*)d_in[4];
  const float* Wr1  = (const float*)d_in[5];
  const float* We1  = (const float*)d_in[6];
  const float* att1 = (const float*)d_in[7];
  const float* b1   = (const float*)d_in[8];
  const float* g1   = (const float*)d_in[9];
  const float* be1  = (const float*)d_in[10];
  const float* Wl2  = (const float*)d_in[11];
  const float* Wr2  = (const float*)d_in[12];
  const float* We2  = (const float*)d_in[13];
  const float* att2 = (const float*)d_in[14];
  const float* b2   = (const float*)d_in[15];
  const float* g2   = (const float*)d_in[16];
  const float* be2  = (const float*)d_in[17];
  const int* srcp = ei;
  const int* dstp = ei + N_EDGES;

  char* ws = (char*)d_ws;
  size_t off = 0;
  auto alloc = [&](size_t bytes) {
    char* p = ws + off; off += (bytes + 15) & ~(size_t)15; return p;
  };
  int*   deg     = (int*)  alloc((size_t)N_NODES * 4);
  float* easum   = (float*)alloc((size_t)N_NODES * 4);
  int*   offsets = (int*)  alloc((size_t)(N_NODES + 1) * 4);
  int*   cursor  = (int*)  alloc((size_t)N_NODES * 4);
  int*   ssrc    = (int*)  alloc((size_t)N_EDGES * 4);
  float* sea     = (float*)alloc((size_t)N_EDGES * 4);
  float* h1      = (float*)alloc((size_t)N_NODES * 256 * 4);
  float* xl2     = (float*)alloc((size_t)N_NODES * 128 * 4);
  float* xr2     = (float*)alloc((size_t)N_NODES * 128 * 4);
  float* pool    = (float*)alloc((size_t)NREP * N_GRAPHS * 128 * 4);
  float* cnt     = (float*)alloc((size_t)NREP * N_GRAPHS * 4);

  // zero counters/accumulators (ws is poisoned 0xAA before every timed call)
  hipMemsetAsync(deg, 0, (char*)ssrc - (char*)deg, stream);
  hipMemsetAsync(pool, 0, ((char*)cnt + (((size_t)NREP*N_GRAPHS*4 + 15) & ~(size_t)15))
                           - (char*)pool, stream);

  k_hist   <<<N_EDGES / 256, 256, 0, stream>>>(dstp, ea, deg, easum);
  k_scan   <<<1, 1024, 0, stream>>>(deg, offsets);
  k_scatter<<<N_EDGES / 256, 256, 0, stream>>>(srcp, dstp, ea, offsets, cursor, ssrc, sea);
  k_gat1   <<<N_NODES / 4, 256, 0, stream>>>(x, Wl1, Wr1, We1, att1, b1, g1, be1,
                                             offsets, ssrc, sea, deg, easum, h1);
  dim3 g5((N_NODES + 63) / 64, 2);
  k_gemm2  <<<g5, 256, 0, stream>>>(h1, Wl2, Wr2, xl2, xr2);
  k_gat2   <<<N_NODES / 4, 256, 0, stream>>>(xl2, xr2, We2, att2, b2, g2, be2,
                                             offsets, ssrc, sea, deg, easum, batch,
                                             pool, cnt);
  k_final  <<<(N_GRAPHS * 128) / 256, 256, 0, stream>>>(pool, cnt, (float*)d_out);
}